// Round 5
// baseline (218.631 us; speedup 1.0000x reference)
//
#include <hip/hip_runtime.h>

#define SQ   2048
#define HEADS 16
#define HD   64
#define EMB  1024

typedef __attribute__((ext_vector_type(2))) __fp16 h2;
typedef __attribute__((ext_vector_type(4))) __fp16 h4;
typedef __attribute__((ext_vector_type(8))) __fp16 h8;
typedef __attribute__((ext_vector_type(4))) float f4;
typedef unsigned short USH;
typedef unsigned int   UI;

__device__ __forceinline__ UI pkh(float a, float b) {   // pack 2 f16 (RTZ)
    h2 v = __builtin_amdgcn_cvt_pkrtz(a, b);
    return __builtin_bit_cast(UI, v);
}

// async global->LDS, 16B per lane (used by gemm_bt only)
__device__ __forceinline__ void glds16(const void* g, void* l) {
    __builtin_amdgcn_global_load_lds(
        (const __attribute__((address_space(1))) unsigned int*)g,
        (__attribute__((address_space(3))) unsigned int*)l, 16, 0, 0);
}

// ---------------------------------------------------------------------------
// Fused Q/K/V per-head projections (y=0,1,2) + Wo fp32->f16 cast (y=3).
// C = W * X^T (operand swap). Q/K written [n,h,s,d]; V written TRANSPOSED
// [n,h,d,s] (the 4 consecutive s per acc register pack into 8B stores),
// eliminating the separate vtrans kernel.
// Q carries 0.125*log2(e) so attention softmax is a bare exp2.
// ---------------------------------------------------------------------------
__global__ __launch_bounds__(256) void proj_fused(
    const float* __restrict__ q_in, const float* __restrict__ k_in,
    const float* __restrict__ v_in, const float* __restrict__ Wq,
    const float* __restrict__ Wk,   const float* __restrict__ Wv,
    const float* __restrict__ Wo,
    USH* __restrict__ Qh, USH* __restrict__ Kh, USH* __restrict__ Vt,
    USH* __restrict__ Wob)
{
    int t = threadIdx.x;
    if (blockIdx.y == 3) {
        int i = blockIdx.x * 256 + t;
        for (int j = 0; j < 4; ++j) {
            float4 v = ((const float4*)Wo)[i + j * 65536];
            uint2 pk; pk.x = pkh(v.x, v.y); pk.y = pkh(v.z, v.w);
            *(uint2*)(Wob + ((size_t)i + (size_t)j * 65536) * 4) = pk;
        }
        return;
    }
    const float* X = (blockIdx.y == 0) ? q_in : (blockIdx.y == 1) ? k_in : v_in;
    const float* W = (blockIdx.y == 0) ? Wq   : (blockIdx.y == 1) ? Wk   : Wv;
    float scale    = (blockIdx.y == 0) ? 0.18033688011112043f : 1.0f;

    __shared__ __align__(16) USH Xl[256][72];
    __shared__ __align__(16) USH Wl[64][72];

    const float4* Xg = (const float4*)(X + (size_t)blockIdx.x * 16384);
    for (int j = 0; j < 16; ++j) {
        int f = t + j * 256;
        float4 v = Xg[f];
        int row = f >> 4; int col = (f & 15) << 2;
        uint2 pk; pk.x = pkh(v.x, v.y); pk.y = pkh(v.z, v.w);
        *(uint2*)&Xl[row][col] = pk;
    }
    const float4* Wg = (const float4*)W;
    for (int j = 0; j < 4; ++j) {
        int f = t + j * 256;
        float4 v = Wg[f];
        int row = f >> 4; int col = (f & 15) << 2;
        uint2 pk; pk.x = pkh(v.x, v.y); pk.y = pkh(v.z, v.w);
        *(uint2*)&Wl[row][col] = pk;
    }
    __syncthreads();

    int wv = t >> 6, lane = t & 63, l4 = lane & 15, quad = lane >> 4;

    h8 wf[4][2], xf[4][2];
    for (int et = 0; et < 4; ++et)
        for (int ks = 0; ks < 2; ++ks)
            wf[et][ks] = *(const h8*)&Wl[et * 16 + l4][ks * 32 + quad * 8];
    for (int rt = 0; rt < 4; ++rt)
        for (int ks = 0; ks < 2; ++ks)
            xf[rt][ks] = *(const h8*)&Xl[wv * 64 + rt * 16 + l4][ks * 32 + quad * 8];

    f4 acc[4][4];
    for (int et = 0; et < 4; ++et)
        for (int rt = 0; rt < 4; ++rt) acc[et][rt] = (f4)(0.0f);
    for (int et = 0; et < 4; ++et)
        for (int rt = 0; rt < 4; ++rt)
            for (int ks = 0; ks < 2; ++ks)
                acc[et][rt] = __builtin_amdgcn_mfma_f32_16x16x32_f16(
                    wf[et][ks], xf[rt][ks], acc[et][rt], 0, 0, 0);

    if (blockIdx.y == 2) {
        // V: write transposed [n,h,d,s]. Thread holds e = et*16+quad*4+j for
        // 4 consecutive s (rt) -> one 8B store per (et,j).
        int ns0 = blockIdx.x * 16 + wv * 4;
        int n = ns0 >> 11, s = ns0 & 2047;
        for (int et = 0; et < 4; ++et)
            for (int j = 0; j < 4; ++j) {
                int e = et * 16 + quad * 4 + j;
                uint2 pk;
                pk.x = pkh(acc[et][0][j], acc[et][1][j]);
                pk.y = pkh(acc[et][2][j], acc[et][3][j]);
                *(uint2*)(Vt + (((size_t)(n * HEADS + l4) * HD + e) * SQ + s)) = pk;
            }
    } else {
        USH* Out = (blockIdx.y == 0) ? Qh : Kh;
        for (int rt = 0; rt < 4; ++rt) {
            int ns = blockIdx.x * 16 + wv * 4 + rt;
            int n = ns >> 11, s = ns & 2047;
            USH* ob = Out + (((size_t)(n * HEADS) + l4) * SQ + s) * HD;
            for (int et = 0; et < 4; ++et) {
                uint2 pk;
                pk.x = pkh(acc[et][rt][0] * scale, acc[et][rt][1] * scale);
                pk.y = pkh(acc[et][rt][2] * scale, acc[et][rt][3] * scale);
                *(uint2*)(ob + et * 16 + quad * 4) = pk;
            }
        }
    }
}

// ---------------------------------------------------------------------------
// Flash attention, no-max exp2 softmax. Wave = 16-key stripe x all 64 q.
// NO LDS / NO barriers in the main loop: each wave consumes a disjoint
// quarter of K/V, so K (QK A-frag, 16B contig) and V^T (PV A-frag, 8B
// contig) are loaded straight from global (L2-resident: 4 heads/XCD = 2MB).
// K register-prefetched one iter ahead; V issued early, consumed after
// softmax. P stays in registers (S^T C-layout == 16x16x16f16 B-layout).
// Cross-wave O/L reduction through LDS once at the end (exact, no max).
// ---------------------------------------------------------------------------
__global__ __launch_bounds__(256, 3) void attn_kernel(
    const USH* __restrict__ Qh, const USH* __restrict__ Kh,
    const USH* __restrict__ Vt, USH* __restrict__ Oh)
{
    __shared__ struct { float Osum[64][68]; float Lsum[64]; } red;  // 17.7 KB

    int t = threadIdx.x, w = t >> 6, lane = t & 63;
    int l4 = lane & 15, quad = lane >> 4;
    int b = blockIdx.x;
    int nh = b & 31;                 // all q-tiles of a head land on one XCD
    int q0 = (b >> 5) * 64;
    const USH* Qg = Qh + ((size_t)nh * SQ + q0) * HD;
    const USH* Kg = Kh + (size_t)nh * SQ * HD;
    const USH* Vg = Vt + (size_t)nh * HD * SQ;

    // Q fragments direct from global (B-operand: B[k=d][n=q], 16B contig)
    h8 bq[4][2];
#pragma unroll
    for (int qt = 0; qt < 4; ++qt)
#pragma unroll
        for (int ks = 0; ks < 2; ++ks)
            bq[qt][ks] = *(const h8*)(Qg + (size_t)(qt * 16 + l4) * HD + ks * 32 + quad * 8);

    f4 o[4][4];
#pragma unroll
    for (int dt = 0; dt < 4; ++dt)
#pragma unroll
        for (int qt = 0; qt < 4; ++qt) o[dt][qt] = (f4)(0.0f);
    float lsum[4] = {0.f, 0.f, 0.f, 0.f};

    // per-lane base pointers
    const USH* kbase = Kg + (size_t)(w * 16 + l4) * HD;       // + kt*4096 + (ks*32 + quad*8)
    const USH* vbase = Vg + (size_t)l4 * SQ + w * 16 + quad * 4; // + dt*16*SQ + kt*64

    h8 ak0 = *(const h8*)(kbase + quad * 8);
    h8 ak1 = *(const h8*)(kbase + 32 + quad * 8);

#pragma unroll 1
    for (int kt = 0; kt < SQ / 64; ++kt) {
        // S^T = K Q^T : C[key=quad*4+r][q=l4]
        f4 sc[4];
#pragma unroll
        for (int qt = 0; qt < 4; ++qt) {
            f4 s = __builtin_amdgcn_mfma_f32_16x16x32_f16(ak0, bq[qt][0], (f4)(0.0f), 0, 0, 0);
            sc[qt] = __builtin_amdgcn_mfma_f32_16x16x32_f16(ak1, bq[qt][1], s, 0, 0, 0);
        }

        // prefetch next K tile (wraps at end; extra loads harmless)
        int ktn = (kt + 1) & 31;
        h8 nk0 = *(const h8*)(kbase + (size_t)ktn * 4096 + quad * 8);
        h8 nk1 = *(const h8*)(kbase + (size_t)ktn * 4096 + 32 + quad * 8);

        // V fragments for this iter (consumed after softmax -> latency hidden)
        h4 av[4];
#pragma unroll
        for (int dt = 0; dt < 4; ++dt)
            av[dt] = *(const h4*)(vbase + (size_t)dt * 16 * SQ + kt * 64);

        // softmax (no max: logits bounded); pack P into B-operand registers
        h4 p[4];
#pragma unroll
        for (int qt = 0; qt < 4; ++qt) {
            float p0 = __builtin_amdgcn_exp2f(sc[qt][0]);
            float p1 = __builtin_amdgcn_exp2f(sc[qt][1]);
            float p2 = __builtin_amdgcn_exp2f(sc[qt][2]);
            float p3 = __builtin_amdgcn_exp2f(sc[qt][3]);
            lsum[qt] += (p0 + p1) + (p2 + p3);
            uint2 u; u.x = pkh(p0, p1); u.y = pkh(p2, p3);
            p[qt] = __builtin_bit_cast(h4, u);
        }

        // O += P V : A = V^T frag, B = P (in registers)
#pragma unroll
        for (int dt = 0; dt < 4; ++dt)
#pragma unroll
            for (int qt = 0; qt < 4; ++qt)
                o[dt][qt] = __builtin_amdgcn_mfma_f32_16x16x16f16(
                    av[dt], p[qt], o[dt][qt], 0, 0, 0);

        ak0 = nk0; ak1 = nk1;
    }

    // quad-reduce lsum (quads hold disjoint keys of this wave's stripe)
#pragma unroll
    for (int qt = 0; qt < 4; ++qt) {
        lsum[qt] += __shfl_xor(lsum[qt], 16, 64);
        lsum[qt] += __shfl_xor(lsum[qt], 32, 64);
    }

    // cross-wave O/L reduction through LDS
    __syncthreads();
    for (int ph = 0; ph < 4; ++ph) {
        if (w == ph) {
            for (int dt = 0; dt < 4; ++dt)
                for (int qt = 0; qt < 4; ++qt) {
                    float* dst = &red.Osum[qt * 16 + l4][dt * 16 + quad * 4];
                    f4 val = o[dt][qt];
                    if (ph) val += *(const f4*)dst;
                    *(f4*)dst = val;
                }
            if (quad == 0)
                for (int qt = 0; qt < 4; ++qt) {
                    int qi = qt * 16 + l4;
                    red.Lsum[qi] = ph ? (red.Lsum[qi] + lsum[qt]) : lsum[qt];
                }
        }
        __syncthreads();
    }

    // epilogue: normalize + f16 store
    int n = nh >> 4, h = nh & 15;
    int q = t >> 2, d0 = (t & 3) * 16;
    float inv = 1.0f / red.Lsum[q];
    float vv[16];
#pragma unroll
    for (int i = 0; i < 4; ++i) {
        f4 x = *(const f4*)&red.Osum[q][d0 + i * 4];
        vv[i * 4 + 0] = x[0] * inv; vv[i * 4 + 1] = x[1] * inv;
        vv[i * 4 + 2] = x[2] * inv; vv[i * 4 + 3] = x[3] * inv;
    }
    uint4 ou0, ou1;
    ou0.x = pkh(vv[0], vv[1]);   ou0.y = pkh(vv[2], vv[3]);
    ou0.z = pkh(vv[4], vv[5]);   ou0.w = pkh(vv[6], vv[7]);
    ou1.x = pkh(vv[8], vv[9]);   ou1.y = pkh(vv[10], vv[11]);
    ou1.z = pkh(vv[12], vv[13]); ou1.w = pkh(vv[14], vv[15]);
    USH* ob = Oh + ((size_t)(n * SQ + q0 + q)) * EMB + h * HD + d0;
    *(uint4*)ob = ou0;
    *(uint4*)(ob + 8) = ou1;
}

// ---------------------------------------------------------------------------
// Output GEMM: C[4096][1024] = A[4096][1024] * B[1024][1024]^T (f16 -> fp32)
// 128x64 tile, BK=64, global_load_lds + XOR swizzle. 512 blocks.
// ---------------------------------------------------------------------------
__global__ __launch_bounds__(256, 4) void gemm_bt(const USH* __restrict__ A,
                                                  const USH* __restrict__ B,
                                                  float* __restrict__ C)
{
    __shared__ __align__(16) USH Al[1024 * 8];   // 128 rows x 64 f16, swizzled
    __shared__ __align__(16) USH Bl[512 * 8];    //  64 rows x 64 f16, swizzled
    int t = threadIdx.x, w = t >> 6, lane = t & 63;
    int l4 = lane & 15, quad = lane >> 4;
    int m0 = blockIdx.y * 128, n0 = blockIdx.x * 64;
    int wm = (w >> 1) * 64, wn = (w & 1) * 32;

    f4 acc[4][2];
    for (int mt = 0; mt < 4; ++mt)
        for (int nt = 0; nt < 2; ++nt) acc[mt][nt] = (f4)(0.0f);

    int aslot[4][2], bslot[2][2];
#pragma unroll
    for (int mt = 0; mt < 4; ++mt)
#pragma unroll
        for (int ks = 0; ks < 2; ++ks) {
            int m = wm + mt * 16 + l4;
            aslot[mt][ks] = m * 8 + ((ks * 4 + quad) ^ (m & 7));
        }
#pragma unroll
    for (int nt = 0; nt < 2; ++nt)
#pragma unroll
        for (int ks = 0; ks < 2; ++ks) {
            int nn = wn + nt * 16 + l4;
            bslot[nt][ks] = nn * 8 + ((ks * 4 + quad) ^ (nn & 7));
        }

    for (int k0 = 0; k0 < 1024; k0 += 64) {
        __syncthreads();
#pragma unroll
        for (int j = 0; j < 4; ++j) {   // A tile 128x64
            int s = j * 256 + t, r = s >> 3, c = (s & 7) ^ (r & 7);
            glds16(A + (size_t)(m0 + r) * 1024 + k0 + c * 8, Al + s * 8);
        }
#pragma unroll
        for (int j = 0; j < 2; ++j) {   // B tile 64x64
            int s = j * 256 + t, r = s >> 3, c = (s & 7) ^ (r & 7);
            glds16(B + (size_t)(n0 + r) * 1024 + k0 + c * 8, Bl + s * 8);
        }
        __syncthreads();

        h8 a[4][2], bf[2][2];
#pragma unroll
        for (int mt = 0; mt < 4; ++mt)
#pragma unroll
            for (int ks = 0; ks < 2; ++ks)
                a[mt][ks] = *(const h8*)(Al + aslot[mt][ks] * 8);
#pragma unroll
        for (int nt = 0; nt < 2; ++nt)
#pragma unroll
            for (int ks = 0; ks < 2; ++ks)
                bf[nt][ks] = *(const h8*)(Bl + bslot[nt][ks] * 8);
#pragma unroll
        for (int mt = 0; mt < 4; ++mt)
#pragma unroll
            for (int nt = 0; nt < 2; ++nt)
#pragma unroll
                for (int ks = 0; ks < 2; ++ks)
                    acc[mt][nt] = __builtin_amdgcn_mfma_f32_16x16x32_f16(
                        a[mt][ks], bf[nt][ks], acc[mt][nt], 0, 0, 0);
    }

    for (int mt = 0; mt < 4; ++mt)
        for (int nt = 0; nt < 2; ++nt)
            for (int r = 0; r < 4; ++r)
                C[(size_t)(m0 + wm + mt * 16 + quad * 4 + r) * 1024 +
                  (n0 + wn + nt * 16 + l4)] = acc[mt][nt][r];
}

// ---------------------------------------------------------------------------
extern "C" void kernel_launch(void* const* d_in, const int* in_sizes, int n_in,
                              void* d_out, int out_size, void* d_ws, size_t ws_size,
                              hipStream_t stream) {
    const float* k_in = (const float*)d_in[0];
    const float* q_in = (const float*)d_in[1];
    const float* v_in = (const float*)d_in[2];
    const float* Wk   = (const float*)d_in[3];
    const float* Wq   = (const float*)d_in[4];
    const float* Wv   = (const float*)d_in[5];
    const float* Wo   = (const float*)d_in[6];
    float* out = (float*)d_out;

    char* ws = (char*)d_ws;
    USH* Qh  = (USH*)(ws);               //  8 MB [n,h,s,d] f16 (scale folded)
    USH* Kh  = (USH*)(ws + 8388608);     //  8 MB [n,h,s,d]
    USH* Vt  = (USH*)(ws + 16777216);    //  8 MB [n,h,d,s]
    USH* Oh  = (USH*)(ws + 25165824);    //  8 MB [n,s,1024]
    USH* Wob = (USH*)(ws + 33554432);    //  2 MB

    proj_fused<<<dim3(256, 4), dim3(256), 0, stream>>>(
        q_in, k_in, v_in, Wq, Wk, Wv, Wo, Qh, Kh, Vt, Wob);
    attn_kernel<<<dim3(1024), dim3(256), 0, stream>>>(Qh, Kh, Vt, Oh);
    gemm_bt<<<dim3(16, 32), dim3(256), 0, stream>>>(Oh, Wob, out);
}

// Round 6
// 206.078 us; speedup vs baseline: 1.0609x; 1.0609x over previous
//
#include <hip/hip_runtime.h>

#define SQ   2048
#define HEADS 16
#define HD   64
#define EMB  1024

typedef __attribute__((ext_vector_type(2))) __fp16 h2;
typedef __attribute__((ext_vector_type(4))) __fp16 h4;
typedef __attribute__((ext_vector_type(8))) __fp16 h8;
typedef __attribute__((ext_vector_type(4))) float f4;
typedef unsigned short USH;
typedef unsigned int   UI;

__device__ __forceinline__ UI pkh(float a, float b) {   // pack 2 f16 (RTZ)
    h2 v = __builtin_amdgcn_cvt_pkrtz(a, b);
    return __builtin_bit_cast(UI, v);
}

// async global->LDS, 16B per lane; LDS dest = wave-uniform base + lane*16
__device__ __forceinline__ void glds16(const void* g, void* l) {
    __builtin_amdgcn_global_load_lds(
        (const __attribute__((address_space(1))) unsigned int*)g,
        (__attribute__((address_space(3))) unsigned int*)l, 16, 0, 0);
}

// ---------------------------------------------------------------------------
// Fused Q/K/V per-head projections (y=0,1,2) + Wo fp32->f16 cast (y=3).
// C = W * X^T (operand swap). Q/K written [n,h,s,d]; V written TRANSPOSED
// [n,h,d,s]. Q carries 0.125*log2(e) so attention softmax is a bare exp2.
// ---------------------------------------------------------------------------
__global__ __launch_bounds__(256) void proj_fused(
    const float* __restrict__ q_in, const float* __restrict__ k_in,
    const float* __restrict__ v_in, const float* __restrict__ Wq,
    const float* __restrict__ Wk,   const float* __restrict__ Wv,
    const float* __restrict__ Wo,
    USH* __restrict__ Qh, USH* __restrict__ Kh, USH* __restrict__ Vt,
    USH* __restrict__ Wob)
{
    int t = threadIdx.x;
    if (blockIdx.y == 3) {
        int i = blockIdx.x * 256 + t;
        for (int j = 0; j < 4; ++j) {
            float4 v = ((const float4*)Wo)[i + j * 65536];
            uint2 pk; pk.x = pkh(v.x, v.y); pk.y = pkh(v.z, v.w);
            *(uint2*)(Wob + ((size_t)i + (size_t)j * 65536) * 4) = pk;
        }
        return;
    }
    const float* X = (blockIdx.y == 0) ? q_in : (blockIdx.y == 1) ? k_in : v_in;
    const float* W = (blockIdx.y == 0) ? Wq   : (blockIdx.y == 1) ? Wk   : Wv;
    float scale    = (blockIdx.y == 0) ? 0.18033688011112043f : 1.0f;

    __shared__ __align__(16) USH Xl[256][72];
    __shared__ __align__(16) USH Wl[64][72];

    const float4* Xg = (const float4*)(X + (size_t)blockIdx.x * 16384);
    for (int j = 0; j < 16; ++j) {
        int f = t + j * 256;
        float4 v = Xg[f];
        int row = f >> 4; int col = (f & 15) << 2;
        uint2 pk; pk.x = pkh(v.x, v.y); pk.y = pkh(v.z, v.w);
        *(uint2*)&Xl[row][col] = pk;
    }
    const float4* Wg = (const float4*)W;
    for (int j = 0; j < 4; ++j) {
        int f = t + j * 256;
        float4 v = Wg[f];
        int row = f >> 4; int col = (f & 15) << 2;
        uint2 pk; pk.x = pkh(v.x, v.y); pk.y = pkh(v.z, v.w);
        *(uint2*)&Wl[row][col] = pk;
    }
    __syncthreads();

    int wv = t >> 6, lane = t & 63, l4 = lane & 15, quad = lane >> 4;

    h8 wf[4][2], xf[4][2];
    for (int et = 0; et < 4; ++et)
        for (int ks = 0; ks < 2; ++ks)
            wf[et][ks] = *(const h8*)&Wl[et * 16 + l4][ks * 32 + quad * 8];
    for (int rt = 0; rt < 4; ++rt)
        for (int ks = 0; ks < 2; ++ks)
            xf[rt][ks] = *(const h8*)&Xl[wv * 64 + rt * 16 + l4][ks * 32 + quad * 8];

    f4 acc[4][4];
    for (int et = 0; et < 4; ++et)
        for (int rt = 0; rt < 4; ++rt) acc[et][rt] = (f4)(0.0f);
    for (int et = 0; et < 4; ++et)
        for (int rt = 0; rt < 4; ++rt)
            for (int ks = 0; ks < 2; ++ks)
                acc[et][rt] = __builtin_amdgcn_mfma_f32_16x16x32_f16(
                    wf[et][ks], xf[rt][ks], acc[et][rt], 0, 0, 0);

    if (blockIdx.y == 2) {
        int ns0 = blockIdx.x * 16 + wv * 4;
        int n = ns0 >> 11, s = ns0 & 2047;
        for (int et = 0; et < 4; ++et)
            for (int j = 0; j < 4; ++j) {
                int e = et * 16 + quad * 4 + j;
                uint2 pk;
                pk.x = pkh(acc[et][0][j], acc[et][1][j]);
                pk.y = pkh(acc[et][2][j], acc[et][3][j]);
                *(uint2*)(Vt + (((size_t)(n * HEADS + l4) * HD + e) * SQ + s)) = pk;
            }
    } else {
        USH* Out = (blockIdx.y == 0) ? Qh : Kh;
        for (int rt = 0; rt < 4; ++rt) {
            int ns = blockIdx.x * 16 + wv * 4 + rt;
            int n = ns >> 11, s = ns & 2047;
            USH* ob = Out + (((size_t)(n * HEADS) + l4) * SQ + s) * HD;
            for (int et = 0; et < 4; ++et) {
                uint2 pk;
                pk.x = pkh(acc[et][rt][0] * scale, acc[et][rt][1] * scale);
                pk.y = pkh(acc[et][rt][2] * scale, acc[et][rt][3] * scale);
                *(uint2*)(ob + et * 16 + quad * 4) = pk;
            }
        }
    }
}

// stage one 64x64 f16 K tile + one 64x64 V^T tile into (swizzled) LDS buffers.
// XOR chunk swizzle applied on the GLOBAL side (glds LDS dest is linear):
// LDS slot s=(r,c) holds global chunk c^(r&7) of row r.
__device__ __forceinline__ void stage_kv(const USH* __restrict__ Kg,
                                         const USH* __restrict__ Vg,
                                         int kt, USH* Kd, USH* Vd,
                                         int w, int lane)
{
#pragma unroll
    for (int j = 0; j < 2; ++j) {
        int s = (w * 2 + j) * 64 + lane;
        int r = s >> 3, c = (s & 7) ^ (r & 7);
        glds16(Kg + kt * 4096 + r * 64 + c * 8, Kd + s * 8);
    }
#pragma unroll
    for (int j = 0; j < 2; ++j) {
        int s = (w * 2 + j) * 64 + lane;
        int r = s >> 3, c = (s & 7) ^ (r & 7);
        glds16(Vg + r * SQ + kt * 64 + c * 8, Vd + s * 8);
    }
}

// ---------------------------------------------------------------------------
// Flash attention, no-max exp2 softmax. Wave = 16-key stripe x all 64 q.
// Double-buffered glds staging: ONE barrier per iter; glds for tile kt+1 is
// issued after the barrier and drained by the NEXT barrier (a full compute
// phase later) -> L2 latency hidden (fixes r4's issue-then-drain stall).
// P stays in registers (S^T C-layout == 16x16x16f16 B-operand layout).
// Cross-wave O/L reduction through LDS once at the end (exact, no max).
// ---------------------------------------------------------------------------
__global__ __launch_bounds__(256, 4) void attn_kernel(
    const USH* __restrict__ Qh, const USH* __restrict__ Kh,
    const USH* __restrict__ Vt, USH* __restrict__ Oh)
{
    __shared__ union {
        struct { USH K[2][4096]; USH V[2][4096]; } s;        // 32 KB
        struct { float Osum[64][68]; float Lsum[64]; } r;    // 17.7 KB
    } lds;

    int t = threadIdx.x, w = t >> 6, lane = t & 63;
    int l4 = lane & 15, quad = lane >> 4;
    int b = blockIdx.x;
    int nh = b & 31;                 // all q-tiles of a head land on one XCD
    int q0 = (b >> 5) * 64;
    const USH* Qg = Qh + ((size_t)nh * SQ + q0) * HD;
    const USH* Kg = Kh + (size_t)nh * SQ * HD;
    const USH* Vg = Vt + (size_t)nh * HD * SQ;

    // Q fragments direct from global (one-time; B-operand layout)
    h8 bq[4][2];
#pragma unroll
    for (int qt = 0; qt < 4; ++qt)
#pragma unroll
        for (int ks = 0; ks < 2; ++ks)
            bq[qt][ks] = *(const h8*)(Qg + (size_t)(qt * 16 + l4) * HD + ks * 32 + quad * 8);

    f4 o[4][4];
#pragma unroll
    for (int dt = 0; dt < 4; ++dt)
#pragma unroll
        for (int qt = 0; qt < 4; ++qt) o[dt][qt] = (f4)(0.0f);
    float lsum[4] = {0.f, 0.f, 0.f, 0.f};

    int key = w * 16 + l4;
    int kslot0 = key * 8 + (quad ^ (key & 7));
    int kslot1 = key * 8 + ((4 + quad) ^ (key & 7));
    int dchunk = w * 2 + (quad >> 1);
    int vbyte  = (quad & 1) * 4;     // USH offset (8 bytes)

    stage_kv(Kg, Vg, 0, lds.s.K[0], lds.s.V[0], w, lane);

    for (int kt = 0; kt < SQ / 64; ++kt) {
        int cur = kt & 1;
        __syncthreads();             // drains glds(tile kt), issued a full phase ago
        if (kt + 1 < SQ / 64)
            stage_kv(Kg, Vg, kt + 1, lds.s.K[cur ^ 1], lds.s.V[cur ^ 1], w, lane);

        // K fragments for this wave's 16-key stripe
        h8 ak0 = *(const h8*)(lds.s.K[cur] + kslot0 * 8);
        h8 ak1 = *(const h8*)(lds.s.K[cur] + kslot1 * 8);

        // S^T = K Q^T : C[key=quad*4+r][q=l4]
        f4 sc[4];
#pragma unroll
        for (int qt = 0; qt < 4; ++qt) {
            f4 s0 = __builtin_amdgcn_mfma_f32_16x16x32_f16(ak0, bq[qt][0], (f4)(0.0f), 0, 0, 0);
            sc[qt] = __builtin_amdgcn_mfma_f32_16x16x32_f16(ak1, bq[qt][1], s0, 0, 0, 0);
        }

        // V fragments (A-operand of 16x16x16: A[m=d][k=quad*4+j], 8B)
        h4 av[4];
#pragma unroll
        for (int dt = 0; dt < 4; ++dt) {
            int d = dt * 16 + l4;
            int vs = d * 8 + (dchunk ^ (d & 7));
            av[dt] = *(const h4*)(lds.s.V[cur] + vs * 8 + vbyte);
        }

        // softmax (no max: logits bounded); pack P into B-operand registers
        h4 p[4];
#pragma unroll
        for (int qt = 0; qt < 4; ++qt) {
            float p0 = __builtin_amdgcn_exp2f(sc[qt][0]);
            float p1 = __builtin_amdgcn_exp2f(sc[qt][1]);
            float p2 = __builtin_amdgcn_exp2f(sc[qt][2]);
            float p3 = __builtin_amdgcn_exp2f(sc[qt][3]);
            lsum[qt] += (p0 + p1) + (p2 + p3);
            uint2 u; u.x = pkh(p0, p1); u.y = pkh(p2, p3);
            p[qt] = __builtin_bit_cast(h4, u);
        }

        // O += P V
#pragma unroll
        for (int dt = 0; dt < 4; ++dt)
#pragma unroll
            for (int qt = 0; qt < 4; ++qt)
                o[dt][qt] = __builtin_amdgcn_mfma_f32_16x16x16f16(
                    av[dt], p[qt], o[dt][qt], 0, 0, 0);
    }

    // quad-reduce lsum (quads hold disjoint keys of this wave's stripe)
#pragma unroll
    for (int qt = 0; qt < 4; ++qt) {
        lsum[qt] += __shfl_xor(lsum[qt], 16, 64);
        lsum[qt] += __shfl_xor(lsum[qt], 32, 64);
    }

    // cross-wave O/L reduction through LDS (union reuse)
    __syncthreads();
    for (int ph = 0; ph < 4; ++ph) {
        if (w == ph) {
            for (int dt = 0; dt < 4; ++dt)
                for (int qt = 0; qt < 4; ++qt) {
                    float* dst = &lds.r.Osum[qt * 16 + l4][dt * 16 + quad * 4];
                    f4 val = o[dt][qt];
                    if (ph) val += *(const f4*)dst;
                    *(f4*)dst = val;
                }
            if (quad == 0)
                for (int qt = 0; qt < 4; ++qt) {
                    int qi = qt * 16 + l4;
                    lds.r.Lsum[qi] = ph ? (lds.r.Lsum[qi] + lsum[qt]) : lsum[qt];
                }
        }
        __syncthreads();
    }

    // epilogue: normalize + f16 store
    int n = nh >> 4, h = nh & 15;
    int q = t >> 2, d0 = (t & 3) * 16;
    float inv = 1.0f / lds.r.Lsum[q];
    float vv[16];
#pragma unroll
    for (int i = 0; i < 4; ++i) {
        f4 x = *(const f4*)&lds.r.Osum[q][d0 + i * 4];
        vv[i * 4 + 0] = x[0] * inv; vv[i * 4 + 1] = x[1] * inv;
        vv[i * 4 + 2] = x[2] * inv; vv[i * 4 + 3] = x[3] * inv;
    }
    uint4 ou0, ou1;
    ou0.x = pkh(vv[0], vv[1]);   ou0.y = pkh(vv[2], vv[3]);
    ou0.z = pkh(vv[4], vv[5]);   ou0.w = pkh(vv[6], vv[7]);
    ou1.x = pkh(vv[8], vv[9]);   ou1.y = pkh(vv[10], vv[11]);
    ou1.z = pkh(vv[12], vv[13]); ou1.w = pkh(vv[14], vv[15]);
    USH* ob = Oh + ((size_t)(n * SQ + q0 + q)) * EMB + h * HD + d0;
    *(uint4*)ob = ou0;
    *(uint4*)(ob + 8) = ou1;
}

// ---------------------------------------------------------------------------
// Output GEMM: C[4096][1024] = A[4096][1024] * B[1024][1024]^T (f16 -> fp32)
// BM=128 BN=64 BK=64, double-buffered glds staging (one barrier/iter),
// 512 blocks, XCD-pinned n-slab (B slab 256KB L2-resident per XCD).
// ---------------------------------------------------------------------------
__global__ __launch_bounds__(256, 3) void gemm_bt(const USH* __restrict__ A,
                                                  const USH* __restrict__ B,
                                                  float* __restrict__ C)
{
    __shared__ union {
        struct { USH A[2][8192]; USH B[2][4096]; } s;        // 48 KB
    } lds;
    int t = threadIdx.x, w = t >> 6, lane = t & 63;
    int l4 = lane & 15, quad = lane >> 4;
    int b = blockIdx.x;
    int n0 = ((b & 7) * 2 + ((b >> 3) & 1)) * 64;    // n-tile pinned per XCD
    int m0 = (b >> 4) * 128;
    int wm = (w >> 1) * 64, wn = (w & 1) * 32;

    f4 acc[4][2];
    for (int mt = 0; mt < 4; ++mt)
        for (int nt = 0; nt < 2; ++nt) acc[mt][nt] = (f4)(0.0f);

    int aslot[4][2], bslot[2][2];
#pragma unroll
    for (int mt = 0; mt < 4; ++mt)
#pragma unroll
        for (int ks = 0; ks < 2; ++ks) {
            int m = wm + mt * 16 + l4;
            aslot[mt][ks] = m * 8 + ((ks * 4 + quad) ^ (m & 7));
        }
#pragma unroll
    for (int nt = 0; nt < 2; ++nt)
#pragma unroll
        for (int ks = 0; ks < 2; ++ks) {
            int nn = wn + nt * 16 + l4;
            bslot[nt][ks] = nn * 8 + ((ks * 4 + quad) ^ (nn & 7));
        }

    // prologue: stage k0=0 into buffer 0
    {
#pragma unroll
        for (int j = 0; j < 4; ++j) {
            int s = (w * 4 + j) * 64 + lane;
            int r = s >> 3, c = (s & 7) ^ (r & 7);
            glds16(A + (size_t)(m0 + r) * 1024 + c * 8, lds.s.A[0] + s * 8);
        }
#pragma unroll
        for (int j = 0; j < 2; ++j) {
            int s = (w * 2 + j) * 64 + lane;
            int r = s >> 3, c = (s & 7) ^ (r & 7);
            glds16(B + (size_t)(n0 + r) * 1024 + c * 8, lds.s.B[0] + s * 8);
        }
    }

    for (int ki = 0; ki < 16; ++ki) {
        int cur = ki & 1;
        __syncthreads();
        if (ki + 1 < 16) {
            int k0 = (ki + 1) * 64;
#pragma unroll
            for (int j = 0; j < 4; ++j) {
                int s = (w * 4 + j) * 64 + lane;
                int r = s >> 3, c = (s & 7) ^ (r & 7);
                glds16(A + (size_t)(m0 + r) * 1024 + k0 + c * 8, lds.s.A[cur ^ 1] + s * 8);
            }
#pragma unroll
            for (int j = 0; j < 2; ++j) {
                int s = (w * 2 + j) * 64 + lane;
                int r = s >> 3, c = (s & 7) ^ (r & 7);
                glds16(B + (size_t)(n0 + r) * 1024 + k0 + c * 8, lds.s.B[cur ^ 1] + s * 8);
            }
        }

        h8 a[4][2], bf[2][2];
#pragma unroll
        for (int mt = 0; mt < 4; ++mt)
#pragma unroll
            for (int ks = 0; ks < 2; ++ks)
                a[mt][ks] = *(const h8*)(lds.s.A[cur] + aslot[mt][ks] * 8);
#pragma unroll
        for (int nt = 0; nt < 2; ++nt)
#pragma unroll
            for (int ks = 0; ks < 2; ++ks)
                bf[nt][ks] = *(const h8*)(lds.s.B[cur] + bslot[nt][ks] * 8);
#pragma unroll
        for (int mt = 0; mt < 4; ++mt)
#pragma unroll
            for (int nt = 0; nt < 2; ++nt)
#pragma unroll
                for (int ks = 0; ks < 2; ++ks)
                    acc[mt][nt] = __builtin_amdgcn_mfma_f32_16x16x32_f16(
                        a[mt][ks], bf[nt][ks], acc[mt][nt], 0, 0, 0);
    }

    for (int mt = 0; mt < 4; ++mt)
        for (int nt = 0; nt < 2; ++nt)
            for (int r = 0; r < 4; ++r)
                C[(size_t)(m0 + wm + mt * 16 + quad * 4 + r) * 1024 +
                  (n0 + wn + nt * 16 + l4)] = acc[mt][nt][r];
}

// ---------------------------------------------------------------------------
extern "C" void kernel_launch(void* const* d_in, const int* in_sizes, int n_in,
                              void* d_out, int out_size, void* d_ws, size_t ws_size,
                              hipStream_t stream) {
    const float* k_in = (const float*)d_in[0];
    const float* q_in = (const float*)d_in[1];
    const float* v_in = (const float*)d_in[2];
    const float* Wk   = (const float*)d_in[3];
    const float* Wq   = (const float*)d_in[4];
    const float* Wv   = (const float*)d_in[5];
    const float* Wo   = (const float*)d_in[6];
    float* out = (float*)d_out;

    char* ws = (char*)d_ws;
    USH* Qh  = (USH*)(ws);               //  8 MB [n,h,s,d] f16 (scale folded)
    USH* Kh  = (USH*)(ws + 8388608);     //  8 MB [n,h,s,d]
    USH* Vt  = (USH*)(ws + 16777216);    //  8 MB [n,h,d,s]
    USH* Oh  = (USH*)(ws + 25165824);    //  8 MB [n,s,1024]
    USH* Wob = (USH*)(ws + 33554432);    //  2 MB

    proj_fused<<<dim3(256, 4), dim3(256), 0, stream>>>(
        q_in, k_in, v_in, Wq, Wk, Wv, Wo, Qh, Kh, Vt, Wob);
    attn_kernel<<<dim3(1024), dim3(256), 0, stream>>>(Qh, Kh, Vt, Oh);
    gemm_bt<<<dim3(512), dim3(256), 0, stream>>>(Oh, Wob, out);
}

// Round 7
// 186.166 us; speedup vs baseline: 1.1744x; 1.1070x over previous
//
#include <hip/hip_runtime.h>

#define SQ   2048
#define HEADS 16
#define HD   64
#define EMB  1024

typedef __attribute__((ext_vector_type(2))) __fp16 h2;
typedef __attribute__((ext_vector_type(4))) __fp16 h4;
typedef __attribute__((ext_vector_type(8))) __fp16 h8;
typedef __attribute__((ext_vector_type(4))) float f4;
typedef unsigned short USH;
typedef unsigned int   UI;

__device__ __forceinline__ UI pkh(float a, float b) {   // pack 2 f16 (RTZ)
    h2 v = __builtin_amdgcn_cvt_pkrtz(a, b);
    return __builtin_bit_cast(UI, v);
}

// async global->LDS, 16B per lane; LDS dest = wave-uniform base + lane*16
__device__ __forceinline__ void glds16(const void* g, void* l) {
    __builtin_amdgcn_global_load_lds(
        (const __attribute__((address_space(1))) unsigned int*)g,
        (__attribute__((address_space(3))) unsigned int*)l, 16, 0, 0);
}

// ---------------------------------------------------------------------------
// Fused Q/K/V per-head projections (y=0,1,2) + Wo fp32->f16 cast (y=3).
// C = W * X^T (operand swap). Q/K written [n,h,s,d]; V written TRANSPOSED
// [n,h,d,s]. Q carries 0.125*log2(e) so attention softmax is a bare exp2.
// ---------------------------------------------------------------------------
__global__ __launch_bounds__(256) void proj_fused(
    const float* __restrict__ q_in, const float* __restrict__ k_in,
    const float* __restrict__ v_in, const float* __restrict__ Wq,
    const float* __restrict__ Wk,   const float* __restrict__ Wv,
    const float* __restrict__ Wo,
    USH* __restrict__ Qh, USH* __restrict__ Kh, USH* __restrict__ Vt,
    USH* __restrict__ Wob)
{
    int t = threadIdx.x;
    if (blockIdx.y == 3) {
        int i = blockIdx.x * 256 + t;
        for (int j = 0; j < 4; ++j) {
            float4 v = ((const float4*)Wo)[i + j * 65536];
            uint2 pk; pk.x = pkh(v.x, v.y); pk.y = pkh(v.z, v.w);
            *(uint2*)(Wob + ((size_t)i + (size_t)j * 65536) * 4) = pk;
        }
        return;
    }
    const float* X = (blockIdx.y == 0) ? q_in : (blockIdx.y == 1) ? k_in : v_in;
    const float* W = (blockIdx.y == 0) ? Wq   : (blockIdx.y == 1) ? Wk   : Wv;
    float scale    = (blockIdx.y == 0) ? 0.18033688011112043f : 1.0f;

    __shared__ __align__(16) USH Xl[256][72];
    __shared__ __align__(16) USH Wl[64][72];

    const float4* Xg = (const float4*)(X + (size_t)blockIdx.x * 16384);
    for (int j = 0; j < 16; ++j) {
        int f = t + j * 256;
        float4 v = Xg[f];
        int row = f >> 4; int col = (f & 15) << 2;
        uint2 pk; pk.x = pkh(v.x, v.y); pk.y = pkh(v.z, v.w);
        *(uint2*)&Xl[row][col] = pk;
    }
    const float4* Wg = (const float4*)W;
    for (int j = 0; j < 4; ++j) {
        int f = t + j * 256;
        float4 v = Wg[f];
        int row = f >> 4; int col = (f & 15) << 2;
        uint2 pk; pk.x = pkh(v.x, v.y); pk.y = pkh(v.z, v.w);
        *(uint2*)&Wl[row][col] = pk;
    }
    __syncthreads();

    int wv = t >> 6, lane = t & 63, l4 = lane & 15, quad = lane >> 4;

    h8 wf[4][2], xf[4][2];
    for (int et = 0; et < 4; ++et)
        for (int ks = 0; ks < 2; ++ks)
            wf[et][ks] = *(const h8*)&Wl[et * 16 + l4][ks * 32 + quad * 8];
    for (int rt = 0; rt < 4; ++rt)
        for (int ks = 0; ks < 2; ++ks)
            xf[rt][ks] = *(const h8*)&Xl[wv * 64 + rt * 16 + l4][ks * 32 + quad * 8];

    f4 acc[4][4];
    for (int et = 0; et < 4; ++et)
        for (int rt = 0; rt < 4; ++rt) acc[et][rt] = (f4)(0.0f);
    for (int et = 0; et < 4; ++et)
        for (int rt = 0; rt < 4; ++rt)
            for (int ks = 0; ks < 2; ++ks)
                acc[et][rt] = __builtin_amdgcn_mfma_f32_16x16x32_f16(
                    wf[et][ks], xf[rt][ks], acc[et][rt], 0, 0, 0);

    if (blockIdx.y == 2) {
        int ns0 = blockIdx.x * 16 + wv * 4;
        int n = ns0 >> 11, s = ns0 & 2047;
        for (int et = 0; et < 4; ++et)
            for (int j = 0; j < 4; ++j) {
                int e = et * 16 + quad * 4 + j;
                uint2 pk;
                pk.x = pkh(acc[et][0][j], acc[et][1][j]);
                pk.y = pkh(acc[et][2][j], acc[et][3][j]);
                *(uint2*)(Vt + (((size_t)(n * HEADS + l4) * HD + e) * SQ + s)) = pk;
            }
    } else {
        USH* Out = (blockIdx.y == 0) ? Qh : Kh;
        for (int rt = 0; rt < 4; ++rt) {
            int ns = blockIdx.x * 16 + wv * 4 + rt;
            int n = ns >> 11, s = ns & 2047;
            USH* ob = Out + (((size_t)(n * HEADS) + l4) * SQ + s) * HD;
            for (int et = 0; et < 4; ++et) {
                uint2 pk;
                pk.x = pkh(acc[et][rt][0] * scale, acc[et][rt][1] * scale);
                pk.y = pkh(acc[et][rt][2] * scale, acc[et][rt][3] * scale);
                *(uint2*)(ob + et * 16 + quad * 4) = pk;
            }
        }
    }
}

// stage one 64x64 f16 K tile + one 64x64 V^T tile into (swizzled) LDS buffers.
__device__ __forceinline__ void stage_kv(const USH* __restrict__ Kg,
                                         const USH* __restrict__ Vg,
                                         int kt, USH* Kd, USH* Vd,
                                         int w, int lane)
{
#pragma unroll
    for (int j = 0; j < 2; ++j) {
        int s = (w * 2 + j) * 64 + lane;
        int r = s >> 3, c = (s & 7) ^ (r & 7);
        glds16(Kg + kt * 4096 + r * 64 + c * 8, Kd + s * 8);
    }
#pragma unroll
    for (int j = 0; j < 2; ++j) {
        int s = (w * 2 + j) * 64 + lane;
        int r = s >> 3, c = (s & 7) ^ (r & 7);
        glds16(Vg + r * SQ + kt * 64 + c * 8, Vd + s * 8);
    }
}

// ---------------------------------------------------------------------------
// Flash attention, no-max exp2 softmax. Wave = 16-key stripe x all 64 q.
// Double-buffered glds staging, ONE barrier per iter.
// launch_bounds(256,3): unified VGPR budget 170/wave -- r6's (256,4) capped
// at 128 and spilled (VGPR=64, +29MB scratch HBM traffic). 64 AGPR acc +
// ~100 arch VGPRs need the 3-wave bound.
// ---------------------------------------------------------------------------
__global__ __launch_bounds__(256, 3) void attn_kernel(
    const USH* __restrict__ Qh, const USH* __restrict__ Kh,
    const USH* __restrict__ Vt, USH* __restrict__ Oh)
{
    __shared__ union {
        struct { USH K[2][4096]; USH V[2][4096]; } s;        // 32 KB
        struct { float Osum[64][68]; float Lsum[64]; } r;    // 17.7 KB
    } lds;

    int t = threadIdx.x, w = t >> 6, lane = t & 63;
    int l4 = lane & 15, quad = lane >> 4;
    int b = blockIdx.x;
    int nh = b & 31;                 // all q-tiles of a head land on one XCD
    int q0 = (b >> 5) * 64;
    const USH* Qg = Qh + ((size_t)nh * SQ + q0) * HD;
    const USH* Kg = Kh + (size_t)nh * SQ * HD;
    const USH* Vg = Vt + (size_t)nh * HD * SQ;

    // Q fragments direct from global (one-time; B-operand layout)
    h8 bq[4][2];
#pragma unroll
    for (int qt = 0; qt < 4; ++qt)
#pragma unroll
        for (int ks = 0; ks < 2; ++ks)
            bq[qt][ks] = *(const h8*)(Qg + (size_t)(qt * 16 + l4) * HD + ks * 32 + quad * 8);

    f4 o[4][4];
#pragma unroll
    for (int dt = 0; dt < 4; ++dt)
#pragma unroll
        for (int qt = 0; qt < 4; ++qt) o[dt][qt] = (f4)(0.0f);
    float lsum[4] = {0.f, 0.f, 0.f, 0.f};

    int key = w * 16 + l4;
    int kslot0 = key * 8 + (quad ^ (key & 7));
    int kslot1 = key * 8 + ((4 + quad) ^ (key & 7));
    int dchunk = w * 2 + (quad >> 1);
    int vbyte  = (quad & 1) * 4;     // USH offset (8 bytes)

    stage_kv(Kg, Vg, 0, lds.s.K[0], lds.s.V[0], w, lane);

    for (int kt = 0; kt < SQ / 64; ++kt) {
        int cur = kt & 1;
        __syncthreads();             // drains glds(tile kt), issued a full phase ago
        if (kt + 1 < SQ / 64)
            stage_kv(Kg, Vg, kt + 1, lds.s.K[cur ^ 1], lds.s.V[cur ^ 1], w, lane);

        // K fragments for this wave's 16-key stripe
        h8 ak0 = *(const h8*)(lds.s.K[cur] + kslot0 * 8);
        h8 ak1 = *(const h8*)(lds.s.K[cur] + kslot1 * 8);

        // S^T = K Q^T : C[key=quad*4+r][q=l4]
        f4 sc[4];
#pragma unroll
        for (int qt = 0; qt < 4; ++qt) {
            f4 s0 = __builtin_amdgcn_mfma_f32_16x16x32_f16(ak0, bq[qt][0], (f4)(0.0f), 0, 0, 0);
            sc[qt] = __builtin_amdgcn_mfma_f32_16x16x32_f16(ak1, bq[qt][1], s0, 0, 0, 0);
        }

        // V fragments (A-operand of 16x16x16: A[m=d][k=quad*4+j], 8B)
        h4 av[4];
#pragma unroll
        for (int dt = 0; dt < 4; ++dt) {
            int d = dt * 16 + l4;
            int vs = d * 8 + (dchunk ^ (d & 7));
            av[dt] = *(const h4*)(lds.s.V[cur] + vs * 8 + vbyte);
        }

        // softmax (no max: logits bounded); pack P into B-operand registers
        h4 p[4];
#pragma unroll
        for (int qt = 0; qt < 4; ++qt) {
            float p0 = __builtin_amdgcn_exp2f(sc[qt][0]);
            float p1 = __builtin_amdgcn_exp2f(sc[qt][1]);
            float p2 = __builtin_amdgcn_exp2f(sc[qt][2]);
            float p3 = __builtin_amdgcn_exp2f(sc[qt][3]);
            lsum[qt] += (p0 + p1) + (p2 + p3);
            uint2 u; u.x = pkh(p0, p1); u.y = pkh(p2, p3);
            p[qt] = __builtin_bit_cast(h4, u);
        }

        // O += P V
#pragma unroll
        for (int dt = 0; dt < 4; ++dt)
#pragma unroll
            for (int qt = 0; qt < 4; ++qt)
                o[dt][qt] = __builtin_amdgcn_mfma_f32_16x16x16f16(
                    av[dt], p[qt], o[dt][qt], 0, 0, 0);
    }

    // quad-reduce lsum (quads hold disjoint keys of this wave's stripe)
#pragma unroll
    for (int qt = 0; qt < 4; ++qt) {
        lsum[qt] += __shfl_xor(lsum[qt], 16, 64);
        lsum[qt] += __shfl_xor(lsum[qt], 32, 64);
    }

    // cross-wave O/L reduction through LDS (union reuse)
    __syncthreads();
    for (int ph = 0; ph < 4; ++ph) {
        if (w == ph) {
            for (int dt = 0; dt < 4; ++dt)
                for (int qt = 0; qt < 4; ++qt) {
                    float* dst = &lds.r.Osum[qt * 16 + l4][dt * 16 + quad * 4];
                    f4 val = o[dt][qt];
                    if (ph) val += *(const f4*)dst;
                    *(f4*)dst = val;
                }
            if (quad == 0)
                for (int qt = 0; qt < 4; ++qt) {
                    int qi = qt * 16 + l4;
                    lds.r.Lsum[qi] = ph ? (lds.r.Lsum[qi] + lsum[qt]) : lsum[qt];
                }
        }
        __syncthreads();
    }

    // epilogue: normalize + f16 store
    int n = nh >> 4, h = nh & 15;
    int q = t >> 2, d0 = (t & 3) * 16;
    float inv = 1.0f / lds.r.Lsum[q];
    float vv[16];
#pragma unroll
    for (int i = 0; i < 4; ++i) {
        f4 x = *(const f4*)&lds.r.Osum[q][d0 + i * 4];
        vv[i * 4 + 0] = x[0] * inv; vv[i * 4 + 1] = x[1] * inv;
        vv[i * 4 + 2] = x[2] * inv; vv[i * 4 + 3] = x[3] * inv;
    }
    uint4 ou0, ou1;
    ou0.x = pkh(vv[0], vv[1]);   ou0.y = pkh(vv[2], vv[3]);
    ou0.z = pkh(vv[4], vv[5]);   ou0.w = pkh(vv[6], vv[7]);
    ou1.x = pkh(vv[8], vv[9]);   ou1.y = pkh(vv[10], vv[11]);
    ou1.z = pkh(vv[12], vv[13]); ou1.w = pkh(vv[14], vv[15]);
    USH* ob = Oh + ((size_t)(n * SQ + q0 + q)) * EMB + h * HD + d0;
    *(uint4*)ob = ou0;
    *(uint4*)(ob + 8) = ou1;
}

// ---------------------------------------------------------------------------
// Output GEMM: C[4096][1024] = A[4096][1024] * B[1024][1024]^T (f16 -> fp32)
// BM=BN=64, BK=64 dbuf (32KB), grid 1024 = 4 blocks/CU, 16 waves/CU.
// m_tile = b & 63 -> XCD = m%8: per-XCD set = 8 A-slabs (1MB) + B (2MB)
// stays L2-resident; 4 desynced barrier domains/CU hide L2 latency.
// ---------------------------------------------------------------------------
__global__ __launch_bounds__(256, 4) void gemm_bt(const USH* __restrict__ A,
                                                  const USH* __restrict__ B,
                                                  float* __restrict__ C)
{
    __shared__ __align__(16) USH Al[2][4096];
    __shared__ __align__(16) USH Bl[2][4096];
    int t = threadIdx.x, w = t >> 6, lane = t & 63;
    int l4 = lane & 15, quad = lane >> 4;
    int b = blockIdx.x;
    int m0 = (b & 63) * 64;
    int n0 = (b >> 6) * 64;
    int wm = (w >> 1) * 32, wn = (w & 1) * 32;

    f4 acc[2][2];
    for (int mt = 0; mt < 2; ++mt)
        for (int nt = 0; nt < 2; ++nt) acc[mt][nt] = (f4)(0.0f);

    int aslot[2][2], bslot[2][2];
#pragma unroll
    for (int mt = 0; mt < 2; ++mt)
#pragma unroll
        for (int ks = 0; ks < 2; ++ks) {
            int m = wm + mt * 16 + l4;
            aslot[mt][ks] = m * 8 + ((ks * 4 + quad) ^ (m & 7));
            int nn = wn + mt * 16 + l4;
            bslot[mt][ks] = nn * 8 + ((ks * 4 + quad) ^ (nn & 7));
        }

    // prologue: stage ki=0 into buffer 0
#pragma unroll
    for (int j = 0; j < 2; ++j) {
        int s = (w * 2 + j) * 64 + lane;
        int r = s >> 3, c = (s & 7) ^ (r & 7);
        glds16(A + (size_t)(m0 + r) * 1024 + c * 8, Al[0] + s * 8);
        glds16(B + (size_t)(n0 + r) * 1024 + c * 8, Bl[0] + s * 8);
    }

    for (int ki = 0; ki < 16; ++ki) {
        int cur = ki & 1;
        __syncthreads();
        if (ki + 1 < 16) {
            int k0 = (ki + 1) * 64;
#pragma unroll
            for (int j = 0; j < 2; ++j) {
                int s = (w * 2 + j) * 64 + lane;
                int r = s >> 3, c = (s & 7) ^ (r & 7);
                glds16(A + (size_t)(m0 + r) * 1024 + k0 + c * 8, Al[cur ^ 1] + s * 8);
                glds16(B + (size_t)(n0 + r) * 1024 + k0 + c * 8, Bl[cur ^ 1] + s * 8);
            }
        }

        h8 a[2][2], bf[2][2];
#pragma unroll
        for (int mt = 0; mt < 2; ++mt)
#pragma unroll
            for (int ks = 0; ks < 2; ++ks) {
                a[mt][ks]  = *(const h8*)(Al[cur] + aslot[mt][ks] * 8);
                bf[mt][ks] = *(const h8*)(Bl[cur] + bslot[mt][ks] * 8);
            }
#pragma unroll
        for (int mt = 0; mt < 2; ++mt)
#pragma unroll
            for (int nt = 0; nt < 2; ++nt)
#pragma unroll
                for (int ks = 0; ks < 2; ++ks)
                    acc[mt][nt] = __builtin_amdgcn_mfma_f32_16x16x32_f16(
                        a[mt][ks], bf[nt][ks], acc[mt][nt], 0, 0, 0);
    }

    for (int mt = 0; mt < 2; ++mt)
        for (int nt = 0; nt < 2; ++nt)
            for (int r = 0; r < 4; ++r)
                C[(size_t)(m0 + wm + mt * 16 + quad * 4 + r) * 1024 +
                  (n0 + wn + nt * 16 + l4)] = acc[mt][nt][r];
}

// ---------------------------------------------------------------------------
extern "C" void kernel_launch(void* const* d_in, const int* in_sizes, int n_in,
                              void* d_out, int out_size, void* d_ws, size_t ws_size,
                              hipStream_t stream) {
    const float* k_in = (const float*)d_in[0];
    const float* q_in = (const float*)d_in[1];
    const float* v_in = (const float*)d_in[2];
    const float* Wk   = (const float*)d_in[3];
    const float* Wq   = (const float*)d_in[4];
    const float* Wv   = (const float*)d_in[5];
    const float* Wo   = (const float*)d_in[6];
    float* out = (float*)d_out;

    char* ws = (char*)d_ws;
    USH* Qh  = (USH*)(ws);               //  8 MB [n,h,s,d] f16 (scale folded)
    USH* Kh  = (USH*)(ws + 8388608);     //  8 MB [n,h,s,d]
    USH* Vt  = (USH*)(ws + 16777216);    //  8 MB [n,h,d,s]
    USH* Oh  = (USH*)(ws + 25165824);    //  8 MB [n,s,1024]
    USH* Wob = (USH*)(ws + 33554432);    //  2 MB

    proj_fused<<<dim3(256, 4), dim3(256), 0, stream>>>(
        q_in, k_in, v_in, Wq, Wk, Wv, Wo, Qh, Kh, Vt, Wob);
    attn_kernel<<<dim3(1024), dim3(256), 0, stream>>>(Qh, Kh, Vt, Oh);
    gemm_bt<<<dim3(1024), dim3(256), 0, stream>>>(Oh, Wob, out);
}